// Round 19
// baseline (1298.562 us; speedup 1.0000x reference)
//
#include <hip/hip_runtime.h>
#include <hip/hip_bf16.h>
#include <math.h>

typedef __bf16 bf16;
typedef bf16 bf16x8 __attribute__((ext_vector_type(8)));
typedef bf16 bf16x4 __attribute__((ext_vector_type(4)));
typedef float f32x4 __attribute__((ext_vector_type(4)));
typedef float f32x16 __attribute__((ext_vector_type(16)));

#define NB    131072
#define DIM   512
#define BATCH 256
#define NPG   512
#define NQ    32
#define NH    8
#define HDIM  64
#define LMD   768
#define NL    2
#define ROWS  (BATCH*NQ)   // 8192

template<int N> struct ic { static constexpr int v = N; };

__device__ __forceinline__ float gelu_f(float x) {
    return 0.5f * x * (1.0f + erff(x * 0.70710678118654752f));
}

// ---------------- small setup kernels ----------------

__global__ void k_init_meta(int* counts, int* inv) {
    int i = blockIdx.x * blockDim.x + threadIdx.x;
    if (i < BATCH) counts[i] = 0;
    for (int j = i; j < BATCH * NPG; j += gridDim.x * blockDim.x) inv[j] = -1;
}

__global__ void k_count(const int* __restrict__ bidx, int* counts) {
    int i = blockIdx.x * blockDim.x + threadIdx.x;
    if (i < NB) atomicAdd(&counts[bidx[i]], 1);
}

__global__ void k_scan(const int* __restrict__ counts, int* __restrict__ starts) {
    __shared__ int sh[BATCH];
    int t = threadIdx.x;
    sh[t] = counts[t];
    __syncthreads();
    for (int o = 1; o < BATCH; o <<= 1) {
        int v = (t >= o) ? sh[t - o] : 0;
        __syncthreads();
        sh[t] += v;
        __syncthreads();
    }
    starts[t] = sh[t] - counts[t];
}

__global__ void k_posinv(const int* __restrict__ bidx, const int* __restrict__ starts,
                         int* __restrict__ pos, int* __restrict__ inv) {
    int i = blockIdx.x * blockDim.x + threadIdx.x;
    if (i < NB) {
        int b = bidx[i];
        int p = i - starts[b];
        pos[i] = p;
        if (p >= 0 && p < NPG) inv[b * NPG + p] = i;
    }
}

__global__ void k_f32_to_bf16(const float* __restrict__ src, bf16* __restrict__ dst, long n4) {
    long i = blockIdx.x * (long)blockDim.x + threadIdx.x;
    long stride = (long)gridDim.x * blockDim.x;
    for (; i < n4; i += stride) {
        f32x4 v = ((const f32x4*)src)[i];
        bf16x4 o = { (bf16)v.x, (bf16)v.y, (bf16)v.z, (bf16)v.w };
        ((bf16x4*)dst)[i] = o;
    }
}

__global__ void k_init_h(const float* __restrict__ qt, float* __restrict__ hf, bf16* __restrict__ hb) {
    long n = (long)ROWS * DIM;
    for (long i = blockIdx.x * (long)blockDim.x + threadIdx.x; i < n;
         i += (long)gridDim.x * blockDim.x) {
        float v = qt[i & (NQ * DIM - 1)];
        hf[i] = v;
        hb[i] = (bf16)v;
    }
}

#define EPI_BF16      0
#define EPI_BF16_GELU 1
#define EPI_F32       2
#define EPI_KV        3

// ===== 128x128 ring GEMM — R19: 16 waves, 32x32/wave via mfma 32x32x16 =====
// Same 4-slot / 3-tile-lookahead / 1-tile-per-barrier schedule (R9..R18;
// R11 ERRATUM: every comp preceded by all-waves counted-vmcnt -> barrier).
// R18 diagnosis: LDS-read-BW-bound (0.125 B/FLOP; 67MB/CU = 218us = dur).
// R19: per-wave 32x32 computed with TWO v_mfma_f32_32x32x16_bf16 instead of
// four 16x16x32 -> same 4 ds_read_b128/tile but 2x FLOP -> 0.0625 B/FLOP.
// Fragments: lane holds row/col = lane&31, k-chunk = 2h + (lane>>5) (8 bf16),
// source-swizzled by ^((row>>1)&3) as everywhere (start banks at HW floor).
// C/D layout (verified m74/m101): col=lane&31, row=(reg&3)+8*(reg>>2)+4*(lane>>5).
// acc = f32x16 (16 AGPR); total regs still <= 64 -> 32 waves/CU retained.

template<int EPI>
__global__ __launch_bounds__(1024)
void k_ring(const bf16* __restrict__ A, const bf16* __restrict__ B,
            const float* __restrict__ bias, void* __restrict__ C,
            int K, int N,
            bf16* __restrict__ vt, const int* __restrict__ bidx,
            const int* __restrict__ pos)
{
    // per slot: A elems [0,4096) (128x32), B elems [4096,8192) (128x32)
    __shared__ bf16 L[4][8192];
    const int tid = threadIdx.x;
    const int w = tid >> 6, lane = tid & 63;

    int nwg = gridDim.x * gridDim.y;
    int lin = blockIdx.y * gridDim.x + blockIdx.x;
    int cpx = nwg >> 3;
    int swzb = (lin & 7) * cpx + (lin >> 3);
    const int n0 = (swzb % gridDim.x) * 128;
    const int m0 = (swzb / gridDim.x) * 128;

    const int wm = w >> 2, wn = w & 3;            // 4 x 4 wave grid
    const int nkt = K >> 5;

    f32x16 acc = {};

    // ---- staging addressing: one load per thread per tile ----
    const int t2 = tid & 511;                      // index within A- or B-half
    const int rSt = t2 >> 2;                       // 0..127
    const int cSw = (t2 & 3) ^ ((rSt >> 1) & 3);   // both-sides swizzle rule
    const bf16* ps = (tid < 512)
        ? A + (size_t)(m0 + rSt) * K + cSw * 8
        : B + (size_t)(n0 + rSt) * K + cSw * 8;
    bf16* lds = &L[0][(tid < 512 ? 0 : 4096) + t2 * 8];

    // ---- hoisted fragment read indices (elements into L[0]) ----
    // mfma_f32_32x32x16 operand: lane holds 8 bf16 at (row = lane&31,
    // k = (lane>>5)*8), two k-halves h=0,1 per 32-wide tile.
    const int lrow = lane & 31;
    const int kg = lane >> 5;
    int iA[2], iB[2];
#pragma unroll
    for (int h = 0; h < 2; ++h) {
        int rowA = wm * 32 + lrow;
        iA[h] = rowA * 32 + ((h * 2 + kg) ^ ((rowA >> 1) & 3)) * 8;
        int colB = wn * 32 + lrow;
        iB[h] = 4096 + colB * 32 + ((h * 2 + kg) ^ ((colB >> 1) & 3)) * 8;
    }
    const bf16* Lf = &L[0][0];

    auto stage = [&](auto S) {   // stages next sequential K-tile into slot S
        constexpr int c = decltype(S)::v;
        __builtin_amdgcn_global_load_lds((const __attribute__((address_space(1))) void*)ps,
            (__attribute__((address_space(3))) void*)(lds + c * 8192), 16, 0, 0);
        ps += 32;
    };

    auto comp = [&](auto S) {
        constexpr int c = decltype(S)::v;
        bf16x8 a0 = *(const bf16x8*)&Lf[iA[0] + c * 8192];
        bf16x8 b0 = *(const bf16x8*)&Lf[iB[0] + c * 8192];
        bf16x8 a1 = *(const bf16x8*)&Lf[iA[1] + c * 8192];
        bf16x8 b1 = *(const bf16x8*)&Lf[iB[1] + c * 8192];
        __builtin_amdgcn_s_setprio(1);
        acc = __builtin_amdgcn_mfma_f32_32x32x16_bf16(a0, b0, acc, 0, 0, 0);
        acc = __builtin_amdgcn_mfma_f32_32x32x16_bf16(a1, b1, acc, 0, 0, 0);
        __builtin_amdgcn_s_setprio(0);
    };

    auto step = [&](auto C_, auto CN_, int t) {
        if (t + 3 < nkt) {
            stage(CN_);
            comp(C_);
            asm volatile("s_waitcnt vmcnt(2)" ::: "memory");
        } else {
            comp(C_);
            asm volatile("s_waitcnt vmcnt(0)" ::: "memory");
        }
        __builtin_amdgcn_s_barrier();
    };

    stage(ic<0>{});                 // tile 0
    stage(ic<1>{});                 // tile 1
    stage(ic<2>{});                 // tile 2
    asm volatile("s_waitcnt vmcnt(2)" ::: "memory");   // tile 0 landed
    __builtin_amdgcn_s_barrier();

    int t = 0;
#pragma unroll 1
    for (; t + 4 <= nkt; t += 4) {
        step(ic<0>{}, ic<3>{}, t);
        step(ic<1>{}, ic<0>{}, t + 1);
        step(ic<2>{}, ic<1>{}, t + 2);
        step(ic<3>{}, ic<2>{}, t + 3);
    }
    if (t < nkt) { step(ic<0>{}, ic<3>{}, t); ++t; }
    if (t < nkt) { step(ic<1>{}, ic<0>{}, t); ++t; }
    if (t < nkt) { step(ic<2>{}, ic<1>{}, t); ++t; }

    // ---- epilogue ----
    // C/D: col = lane&31 (constant per lane!), row = (r&3)+8*(r>>2)+4*kg.
    const int lcol = lrow;
    float bvl = bias ? bias[n0 + wn * 32 + lcol] : 0.0f;

    if constexpr (EPI == EPI_F32) {
        float* out = (float*)C;
#pragma unroll
        for (int r = 0; r < 16; ++r) {
            int row = (r & 3) + 8 * (r >> 2) + 4 * kg;
            out[(size_t)(m0 + wm * 32 + row) * N + (n0 + wn * 32 + lcol)] = acc[r] + bvl;
        }
    } else {
        __syncthreads();   // LDS free for reuse
        // per-wave repack region: [32][36] = 1152 elems; 16 x 1152 <= 32768.
        bf16* reg = &L[0][0] + w * 1152;
        const bool vpart = (EPI == EPI_KV) && (n0 >= 512);
#pragma unroll
        for (int r = 0; r < 16; ++r) {
            float val = acc[r] + bvl;
            if constexpr (EPI == EPI_BF16_GELU) val = gelu_f(val);
            int rm = (r & 3) + 8 * (r >> 2) + 4 * kg;   // local row 0..31
            if (vpart) reg[lcol * 36 + rm] = (bf16)val;   // [ch][node]
            else       reg[rm * 36 + lcol] = (bf16)val;   // [row][col]
        }
        if (!vpart) {
            bf16* outp = (bf16*)C;
            size_t ld = (EPI == EPI_KV) ? 512 : (size_t)N;
#pragma unroll
            for (int it = 0; it < 4; ++it) {
                int rm = it * 8 + (lane >> 3);
                int cn = (lane & 7) * 4;
                bf16x4 v = *(const bf16x4*)&reg[rm * 36 + cn];
                *(bf16x4*)&outp[(size_t)(m0 + wm * 32 + rm) * ld + (n0 + wn * 32 + cn)] = v;
            }
        } else if constexpr (EPI == EPI_KV) {
            int nb = m0 + wm * 32;
            int g0 = bidx[nb], p0 = pos[nb];
            bool fast = (bidx[nb + 31] == g0) && (pos[nb + 31] == p0 + 31) &&
                        ((p0 & 3) == 0) && (p0 >= 0) && (p0 + 31 < NPG);
            int ch0 = (n0 - 512) + wn * 32;
            if (fast) {
#pragma unroll
                for (int it = 0; it < 4; ++it) {
                    int ch = it * 8 + (lane >> 3);
                    int np = (lane & 7) * 4;
                    bf16x4 v = *(const bf16x4*)&reg[ch * 36 + np];
                    *(bf16x4*)&vt[((size_t)g0 * 512 + ch0 + ch) * 512 + p0 + np] = v;
                }
            } else {
                for (int it = 0; it < 4; ++it) {
                    int ch = it * 8 + (lane >> 3);
#pragma unroll
                    for (int e = 0; e < 4; ++e) {
                        int node = nb + (lane & 7) * 4 + e;
                        int g = bidx[node], p = pos[node];
                        if (p >= 0 && p < NPG)
                            vt[((size_t)g * 512 + ch0 + ch) * 512 + p] = reg[ch * 36 + (lane & 7) * 4 + e];
                    }
                }
            }
        }
    }
}

// ---------------- fused attention: one block per (graph, head) ----------------
// R14: S f16 -> 2 blocks/CU. R15: S/P aliased 33KB -> 4 blocks/CU.
// R16: PV vb hoisted out of mf loop + batched 8-deep.

__global__ __launch_bounds__(256)
void k_attn(const bf16* __restrict__ q, const bf16* __restrict__ kbuf,
            const bf16* __restrict__ vt, const int* __restrict__ inv,
            const int* __restrict__ counts, bf16* __restrict__ ctx)
{
    __shared__ unsigned short SP[32][520];   // f16 scores, then bf16 probs
    const int bh = blockIdx.x;
    const int b = bh >> 3, h = bh & 7;
    const int tid = threadIdx.x;
    const int w = tid >> 6, l = tid & 63;
    const int lr = l & 15, lg = l >> 4;
    const int cnt = counts[b];

    bf16x8 qa[2][2];
#pragma unroll
    for (int mf = 0; mf < 2; ++mf)
#pragma unroll
        for (int ks = 0; ks < 2; ++ks)
            qa[mf][ks] = *(const bf16x8*)&q[(size_t)(b * NQ + mf * 16 + lr) * DIM + h * HDIM + ks * 32 + lg * 8];

    const int nc0 = w * 128;
#pragma unroll
    for (int nf = 0; nf < 8; ++nf) {
        int node = nc0 + nf * 16 + lr;
        int idx = inv[b * NPG + node];
        const bf16* krow = kbuf + (size_t)(idx < 0 ? 0 : idx) * 512 + h * HDIM;
        bf16x8 kb0 = *(const bf16x8*)&krow[lg * 8];
        bf16x8 kb1 = *(const bf16x8*)&krow[32 + lg * 8];
#pragma unroll
        for (int mf = 0; mf < 2; ++mf) {
            f32x4 a = {0.f, 0.f, 0.f, 0.f};
            a = __builtin_amdgcn_mfma_f32_16x16x32_bf16(qa[mf][0], kb0, a, 0, 0, 0);
            a = __builtin_amdgcn_mfma_f32_16x16x32_bf16(qa[mf][1], kb1, a, 0, 0, 0);
#pragma unroll
            for (int r = 0; r < 4; ++r)
                *(_Float16*)&SP[mf * 16 + lg * 4 + r][node] = (_Float16)(a[r] * 0.125f);
        }
    }
    __syncthreads();

#pragma unroll 1
    for (int qi = w * 8; qi < w * 8 + 8; ++qi) {
        float sv[8];
        float mx = -3.4e38f;
#pragma unroll
        for (int e = 0; e < 8; ++e) {
            int c = l + 64 * e;
            sv[e] = (c < cnt) ? (float)*(const _Float16*)&SP[qi][c] : -3.4e38f;
            mx = fmaxf(mx, sv[e]);
        }
#pragma unroll
        for (int o = 32; o; o >>= 1) mx = fmaxf(mx, __shfl_xor(mx, o));
        float sum = 0.f, ev[8];
#pragma unroll
        for (int e = 0; e < 8; ++e) {
            int c = l + 64 * e;
            float s = (c < cnt) ? __expf(sv[e] - mx) : 0.0f;
            ev[e] = s; sum += s;
        }
#pragma unroll
        for (int o = 32; o; o >>= 1) sum += __shfl_xor(sum, o);
        float inv_s = sum > 0.f ? 1.0f / sum : 0.0f;
#pragma unroll
        for (int e = 0; e < 8; ++e)
            *(bf16*)&SP[qi][l + 64 * e] = (bf16)(ev[e] * inv_s);
    }
    __syncthreads();

    // phase 3: ctx = P @ V; vb hoisted (mf-independent), batched 8-deep
    const bf16* vrow = vt + ((size_t)b * 512 + h * HDIM + w * 16 + lr) * 512;
    f32x4 a2[2] = {};
#pragma unroll
    for (int kc8 = 0; kc8 < 2; ++kc8) {
        bf16x8 vb[8];
#pragma unroll
        for (int j = 0; j < 8; ++j)
            vb[j] = *(const bf16x8*)&vrow[(kc8 * 8 + j) * 32 + lg * 8];
#pragma unroll
        for (int mf = 0; mf < 2; ++mf)
#pragma unroll
            for (int j = 0; j < 8; ++j) {
                bf16x8 pa = *(const bf16x8*)&SP[mf * 16 + lr][(kc8 * 8 + j) * 32 + lg * 8];
                a2[mf] = __builtin_amdgcn_mfma_f32_16x16x32_bf16(pa, vb[j], a2[mf], 0, 0, 0);
            }
    }
#pragma unroll
    for (int mf = 0; mf < 2; ++mf)
#pragma unroll
        for (int r = 0; r < 4; ++r)
            ctx[(size_t)(b * NQ + mf * 16 + lg * 4 + r) * DIM + h * HDIM + w * 16 + lr] = (bf16)a2[mf][r];
}

// ---------------- layernorm (one wave per row, f32x4 vectorized) ----------------

template<int MODE>
__global__ __launch_bounds__(256)
void k_ln(const float* __restrict__ x, const float* __restrict__ resid,
          const float* __restrict__ g, const float* __restrict__ bt,
          float* __restrict__ of, bf16* __restrict__ ob, int D)
{
    int wid = blockIdx.x * 4 + (threadIdx.x >> 6);
    int l = threadIdx.x & 63;
    const int nv = D >> 8;     // 2 (D=512) or 3 (D=768)
    const float* xr = x + (size_t)wid * D;
    f32x4 v[3];
    float s = 0.f;
    for (int e = 0; e < nv; ++e) {
        int c = e * 256 + l * 4;
        f32x4 t = *(const f32x4*)&xr[c];
        if (MODE == 0) {
            f32x4 rr = *(const f32x4*)&resid[(size_t)wid * D + c];
            t.x += rr.x; t.y += rr.y; t.z += rr.z; t.w += rr.w;
        }
        v[e] = t; s += t.x + t.y + t.z + t.w;
    }
#pragma unroll
    for (int o = 32; o; o >>= 1) s += __shfl_xor(s, o);
    float mu = s / D;
    float s2 = 0.f;
    for (int e = 0; e < nv; ++e) {
#pragma unroll
        for (int j = 0; j < 4; ++j) { float d = v[e][j] - mu; s2 += d * d; }
    }
#pragma unroll
    for (int o = 32; o; o >>= 1) s2 += __shfl_xor(s2, o);
    float rst = rsqrtf(s2 / D + 1e-5f);
    for (int e = 0; e < nv; ++e) {
        int c = e * 256 + l * 4;
        f32x4 gv = *(const f32x4*)&g[c];
        f32x4 bv = *(const f32x4*)&bt[c];
        f32x4 y;
#pragma unroll
        for (int j = 0; j < 4; ++j) {
            float yy = (v[e][j] - mu) * rst * gv[j] + bv[j];
            if (MODE == 1) yy = gelu_f(yy);
            y[j] = yy;
        }
        if (MODE == 0) *(f32x4*)&of[(size_t)wid * D + c] = y;
        bf16x4 yb = { (bf16)y.x, (bf16)y.y, (bf16)y.z, (bf16)y.w };
        *(bf16x4*)&ob[(size_t)wid * D + c] = yb;
    }
}

// ---------------- host launch ----------------

extern "C" void kernel_launch(void* const* d_in, const int* in_sizes, int n_in,
                              void* d_out, int out_size, void* d_ws, size_t ws_size,
                              hipStream_t stream)
{
    const float* node = (const float*)d_in[0];
    const float* qt   = (const float*)d_in[1];
    const float* ipw  = (const float*)d_in[2];
    const float* ipb  = (const float*)d_in[3];
    const float* opw  = (const float*)d_in[4];
    const float* opb  = (const float*)d_in[5];
    const float* f1w  = (const float*)d_in[6];
    const float* f1b  = (const float*)d_in[7];
    const float* f2w  = (const float*)d_in[8];
    const float* f2b  = (const float*)d_in[9];
    const float* ln1g = (const float*)d_in[10];
    const float* ln1b = (const float*)d_in[11];
    const float* ln2g = (const float*)d_in[12];
    const float* ln2b = (const float*)d_in[13];
    const float* ow1  = (const float*)d_in[14];
    const float* ob1  = (const float*)d_in[15];
    const float* olng = (const float*)d_in[16];
    const float* olnb = (const float*)d_in[17];
    const float* ow2  = (const float*)d_in[18];
    const float* ob2  = (const float*)d_in[19];
    const int*   bidx = (const int*)d_in[20];

    char* ws = (char*)d_ws;
    size_t off = 0;
    auto alloc = [&](size_t bytes) {
        void* p = ws + off;
        off += (bytes + 255) & ~(size_t)255;
        return p;
    };

    int*  counts = (int*)alloc(BATCH * 4);
    int*  starts = (int*)alloc(BATCH * 4);
    int*  pos    = (int*)alloc((size_t)NB * 4);
    int*  inv    = (int*)alloc((size_t)BATCH * NPG * 4);
    bf16* nodeb  = (bf16*)alloc((size_t)NB * DIM * 2);
    bf16* kbuf   = (bf16*)alloc((size_t)NB * DIM * 2);
    bf16* vtb    = (bf16*)alloc((size_t)BATCH * DIM * NPG * 2);
    bf16* wip    = (bf16*)alloc((size_t)NL * 1536 * DIM * 2);
    bf16* wop    = (bf16*)alloc((size_t)NL * DIM * DIM * 2);
    bf16* wf1    = (bf16*)alloc((size_t)NL * 2048 * DIM * 2);
    bf16* wf2    = (bf16*)alloc((size_t)NL * DIM * 2048 * 2);
    bf16* wo1    = (bf16*)alloc((size_t)LMD * DIM * 2);
    bf16* wo2    = (bf16*)alloc((size_t)LMD * LMD * 2);
    float* hf    = (float*)alloc((size_t)ROWS * DIM * 4);
    bf16* hb     = (bf16*)alloc((size_t)ROWS * DIM * 2);
    bf16* qb     = (bf16*)alloc((size_t)ROWS * DIM * 2);
    bf16* ctxb   = (bf16*)alloc((size_t)ROWS * DIM * 2);
    float* tmp   = (float*)alloc((size_t)ROWS * LMD * 4);
    bf16* fmid   = (bf16*)alloc((size_t)ROWS * 2048 * 2);
    bf16* omid   = (bf16*)alloc((size_t)ROWS * LMD * 2);
    (void)ws_size; (void)in_sizes; (void)n_in; (void)out_size;

    k_init_meta<<<512, 256, 0, stream>>>(counts, inv);
    k_count<<<NB / 256, 256, 0, stream>>>(bidx, counts);
    k_scan<<<1, BATCH, 0, stream>>>(counts, starts);
    k_posinv<<<NB / 256, 256, 0, stream>>>(bidx, starts, pos, inv);
    k_f32_to_bf16<<<2048, 256, 0, stream>>>(node, nodeb, (long)NB * DIM / 4);
    k_f32_to_bf16<<<256, 256, 0, stream>>>(ipw, wip, (long)NL * 1536 * DIM / 4);
    k_f32_to_bf16<<<256, 256, 0, stream>>>(opw, wop, (long)NL * DIM * DIM / 4);
    k_f32_to_bf16<<<256, 256, 0, stream>>>(f1w, wf1, (long)NL * 2048 * DIM / 4);
    k_f32_to_bf16<<<256, 256, 0, stream>>>(f2w, wf2, (long)NL * DIM * 2048 / 4);
    k_f32_to_bf16<<<256, 256, 0, stream>>>(ow1, wo1, (long)LMD * DIM / 4);
    k_f32_to_bf16<<<256, 256, 0, stream>>>(ow2, wo2, (long)LMD * LMD / 4);
    k_init_h<<<2048, 256, 0, stream>>>(qt, hf, hb);

    for (int lyr = 0; lyr < NL; ++lyr) {
        const bf16* wq  = wip + (size_t)lyr * 1536 * DIM;
        const bf16* wkv = wq + (size_t)512 * DIM;
        const float* bq  = ipb + lyr * 1536;
        const float* bkv = bq + 512;

        dim3 gkv(1024 / 128, NB / 128);
        k_ring<EPI_KV><<<gkv, 1024, 0, stream>>>(nodeb, wkv, bkv, kbuf, DIM, 1024, vtb, bidx, pos);

        dim3 gq(DIM / 128, ROWS / 128);
        k_ring<EPI_BF16><<<gq, 1024, 0, stream>>>(hb, wq, bq, qb, DIM, DIM,
                                                  nullptr, nullptr, nullptr);

        k_attn<<<BATCH * NH, 256, 0, stream>>>(qb, kbuf, vtb, inv, counts, ctxb);

        k_ring<EPI_F32><<<gq, 1024, 0, stream>>>(ctxb, wop + (size_t)lyr * DIM * DIM,
                                                 opb + lyr * DIM, tmp, DIM, DIM,
                                                 nullptr, nullptr, nullptr);
        k_ln<0><<<ROWS / 4, 256, 0, stream>>>(tmp, hf, ln1g + lyr * DIM, ln1b + lyr * DIM, hf, hb, DIM);

        dim3 gf1(2048 / 128, ROWS / 128);
        k_ring<EPI_BF16_GELU><<<gf1, 1024, 0, stream>>>(hb, wf1 + (size_t)lyr * 2048 * DIM,
                                                        f1b + lyr * 2048, fmid, DIM, 2048,
                                                        nullptr, nullptr, nullptr);
        k_ring<EPI_F32><<<gq, 1024, 0, stream>>>(fmid, wf2 + (size_t)lyr * DIM * 2048,
                                                 f2b + lyr * DIM, tmp, 2048, DIM,
                                                 nullptr, nullptr, nullptr);
        k_ln<0><<<ROWS / 4, 256, 0, stream>>>(tmp, hf, ln2g + lyr * DIM, ln2b + lyr * DIM, hf, hb, DIM);
    }

    dim3 go1(LMD / 128, ROWS / 128);
    k_ring<EPI_F32><<<go1, 1024, 0, stream>>>(hb, wo1, ob1, tmp, DIM, LMD,
                                              nullptr, nullptr, nullptr);
    k_ln<1><<<ROWS / 4, 256, 0, stream>>>(tmp, nullptr, olng, olnb, nullptr, omid, LMD);
    k_ring<EPI_F32><<<go1, 1024, 0, stream>>>(omid, wo2, ob2, (float*)d_out, LMD, LMD,
                                              nullptr, nullptr, nullptr);
}

// Round 20
// 1142.475 us; speedup vs baseline: 1.1366x; 1.1366x over previous
//
#include <hip/hip_runtime.h>
#include <hip/hip_bf16.h>
#include <math.h>

typedef __bf16 bf16;
typedef bf16 bf16x8 __attribute__((ext_vector_type(8)));
typedef bf16 bf16x4 __attribute__((ext_vector_type(4)));
typedef float f32x4 __attribute__((ext_vector_type(4)));

#define NB    131072
#define DIM   512
#define BATCH 256
#define NPG   512
#define NQ    32
#define NH    8
#define HDIM  64
#define LMD   768
#define NL    2
#define ROWS  (BATCH*NQ)   // 8192

template<int N> struct ic { static constexpr int v = N; };

__device__ __forceinline__ float gelu_f(float x) {
    return 0.5f * x * (1.0f + erff(x * 0.70710678118654752f));
}

// ---------------- small setup kernels ----------------

__global__ void k_init_meta(int* counts, int* inv) {
    int i = blockIdx.x * blockDim.x + threadIdx.x;
    if (i < BATCH) counts[i] = 0;
    for (int j = i; j < BATCH * NPG; j += gridDim.x * blockDim.x) inv[j] = -1;
}

__global__ void k_count(const int* __restrict__ bidx, int* counts) {
    int i = blockIdx.x * blockDim.x + threadIdx.x;
    if (i < NB) atomicAdd(&counts[bidx[i]], 1);
}

__global__ void k_scan(const int* __restrict__ counts, int* __restrict__ starts) {
    __shared__ int sh[BATCH];
    int t = threadIdx.x;
    sh[t] = counts[t];
    __syncthreads();
    for (int o = 1; o < BATCH; o <<= 1) {
        int v = (t >= o) ? sh[t - o] : 0;
        __syncthreads();
        sh[t] += v;
        __syncthreads();
    }
    starts[t] = sh[t] - counts[t];
}

__global__ void k_posinv(const int* __restrict__ bidx, const int* __restrict__ starts,
                         int* __restrict__ pos, int* __restrict__ inv) {
    int i = blockIdx.x * blockDim.x + threadIdx.x;
    if (i < NB) {
        int b = bidx[i];
        int p = i - starts[b];
        pos[i] = p;
        if (p >= 0 && p < NPG) inv[b * NPG + p] = i;
    }
}

__global__ void k_f32_to_bf16(const float* __restrict__ src, bf16* __restrict__ dst, long n4) {
    long i = blockIdx.x * (long)blockDim.x + threadIdx.x;
    long stride = (long)gridDim.x * blockDim.x;
    for (; i < n4; i += stride) {
        f32x4 v = ((const f32x4*)src)[i];
        bf16x4 o = { (bf16)v.x, (bf16)v.y, (bf16)v.z, (bf16)v.w };
        ((bf16x4*)dst)[i] = o;
    }
}

__global__ void k_init_h(const float* __restrict__ qt, float* __restrict__ hf, bf16* __restrict__ hb) {
    long n = (long)ROWS * DIM;
    for (long i = blockIdx.x * (long)blockDim.x + threadIdx.x; i < n;
         i += (long)gridDim.x * blockDim.x) {
        float v = qt[i & (NQ * DIM - 1)];
        hf[i] = v;
        hb[i] = (bf16)v;
    }
}

#define EPI_BF16      0
#define EPI_BF16_GELU 1
#define EPI_F32       2
#define EPI_KV        3

// ===== 128x128 ring GEMM — R18 (final): 16 waves (4Mx4N), 32x32/wave =====
// 4-slot / 3-tile-lookahead / 1-tile-per-barrier schedule (verified R9/R13/
// R17/R18; R11 ERRATUM: every comp preceded by all-waves counted-vmcnt ->
// barrier). 1024 threads = 16 waves, per-wave 32x32 (acc[2][2] = 16 AGPR,
// av[2]+bv[2], one staging pointer/thread) -> <=64 total regs -> 32 waves/CU
// (2 blocks x 16), 84% occupancy (measured). R19 ERRATUM: replacing the four
// 16x16x32 MFMAs with two 32x32x16 blew up LDS bank conflicts 9x (the
// 32-row x 2-kgroup fragment read defeats the (row>>1)&3 swizzle) — kept
// 16x16x32.
// Staging: threads <512 stage A rows, >=512 stage B rows; 1 load/thread/tile.
// Ledger: steady in-flight/thread after stage = 3 (t+1..t+3); vmcnt(2)
// forces t+1, leaves 2 crossing the barrier.

template<int EPI>
__global__ __launch_bounds__(1024)
void k_ring(const bf16* __restrict__ A, const bf16* __restrict__ B,
            const float* __restrict__ bias, void* __restrict__ C,
            int K, int N,
            bf16* __restrict__ vt, const int* __restrict__ bidx,
            const int* __restrict__ pos)
{
    // per slot: A elems [0,4096) (128x32), B elems [4096,8192) (128x32)
    __shared__ bf16 L[4][8192];
    const int tid = threadIdx.x;
    const int w = tid >> 6, lane = tid & 63;

    int nwg = gridDim.x * gridDim.y;
    int lin = blockIdx.y * gridDim.x + blockIdx.x;
    int cpx = nwg >> 3;
    int swzb = (lin & 7) * cpx + (lin >> 3);
    const int n0 = (swzb % gridDim.x) * 128;
    const int m0 = (swzb / gridDim.x) * 128;

    const int wm = w >> 2, wn = w & 3;            // 4 x 4 wave grid
    const int lr = lane & 15, lg = lane >> 4;
    const int nkt = K >> 5;

    f32x4 acc[2][2] = {};

    // ---- staging addressing: one load per thread per tile ----
    const int t2 = tid & 511;                      // index within A- or B-half
    const int rSt = t2 >> 2;                       // 0..127
    const int cSw = (t2 & 3) ^ ((rSt >> 1) & 3);   // both-sides swizzle rule
    const bf16* ps = (tid < 512)
        ? A + (size_t)(m0 + rSt) * K + cSw * 8
        : B + (size_t)(n0 + rSt) * K + cSw * 8;
    bf16* lds = &L[0][(tid < 512 ? 0 : 4096) + t2 * 8];

    // ---- hoisted fragment read indices (elements into L[0]) ----
    int iA[2], iB[2];
#pragma unroll
    for (int mf = 0; mf < 2; ++mf) {
        int row = wm * 32 + mf * 16 + lr;
        iA[mf] = row * 32 + (lg ^ ((row >> 1) & 3)) * 8;
    }
#pragma unroll
    for (int nf = 0; nf < 2; ++nf) {
        int col = wn * 32 + nf * 16 + lr;
        iB[nf] = 4096 + col * 32 + (lg ^ ((col >> 1) & 3)) * 8;
    }
    const bf16* Lf = &L[0][0];

    auto stage = [&](auto S) {   // stages next sequential K-tile into slot S
        constexpr int c = decltype(S)::v;
        __builtin_amdgcn_global_load_lds((const __attribute__((address_space(1))) void*)ps,
            (__attribute__((address_space(3))) void*)(lds + c * 8192), 16, 0, 0);
        ps += 32;
    };

    auto comp = [&](auto S) {
        constexpr int c = decltype(S)::v;
        bf16x8 av[2], bv[2];
#pragma unroll
        for (int mf = 0; mf < 2; ++mf)
            av[mf] = *(const bf16x8*)&Lf[iA[mf] + c * 8192];
#pragma unroll
        for (int nf = 0; nf < 2; ++nf)
            bv[nf] = *(const bf16x8*)&Lf[iB[nf] + c * 8192];
        __builtin_amdgcn_s_setprio(1);
#pragma unroll
        for (int mf = 0; mf < 2; ++mf)
#pragma unroll
            for (int nf = 0; nf < 2; ++nf)
                acc[mf][nf] = __builtin_amdgcn_mfma_f32_16x16x32_bf16(av[mf], bv[nf], acc[mf][nf], 0, 0, 0);
        __builtin_amdgcn_s_setprio(0);
    };

    auto step = [&](auto C_, auto CN_, int t) {
        if (t + 3 < nkt) {
            stage(CN_);
            comp(C_);
            asm volatile("s_waitcnt vmcnt(2)" ::: "memory");
        } else {
            comp(C_);
            asm volatile("s_waitcnt vmcnt(0)" ::: "memory");
        }
        __builtin_amdgcn_s_barrier();
    };

    stage(ic<0>{});                 // tile 0
    stage(ic<1>{});                 // tile 1
    stage(ic<2>{});                 // tile 2
    asm volatile("s_waitcnt vmcnt(2)" ::: "memory");   // tile 0 landed
    __builtin_amdgcn_s_barrier();

    int t = 0;
#pragma unroll 1
    for (; t + 4 <= nkt; t += 4) {
        step(ic<0>{}, ic<3>{}, t);
        step(ic<1>{}, ic<0>{}, t + 1);
        step(ic<2>{}, ic<1>{}, t + 2);
        step(ic<3>{}, ic<2>{}, t + 3);
    }
    if (t < nkt) { step(ic<0>{}, ic<3>{}, t); ++t; }
    if (t < nkt) { step(ic<1>{}, ic<0>{}, t); ++t; }
    if (t < nkt) { step(ic<2>{}, ic<1>{}, t); ++t; }

    // ---- epilogue ----
    float bvl[2];
#pragma unroll
    for (int nf = 0; nf < 2; ++nf)
        bvl[nf] = bias ? bias[n0 + wn * 32 + nf * 16 + lr] : 0.0f;

    if constexpr (EPI == EPI_F32) {
        float* out = (float*)C;
#pragma unroll
        for (int mfl = 0; mfl < 2; ++mfl) {
#pragma unroll
            for (int nf = 0; nf < 2; ++nf) {
                int c = n0 + wn * 32 + nf * 16 + lr;
#pragma unroll
                for (int r = 0; r < 4; ++r)
                    out[(size_t)(m0 + wm * 32 + mfl * 16 + lg * 4 + r) * N + c] = acc[mfl][nf][r] + bvl[nf];
            }
        }
    } else {
        __syncthreads();   // LDS free for reuse
        // per-wave repack region: [32][36] = 1152 elems; 16 x 1152 <= 32768.
        bf16* reg = &L[0][0] + w * 1152;
        const bool vpart = (EPI == EPI_KV) && (n0 >= 512);
#pragma unroll
        for (int mfl = 0; mfl < 2; ++mfl) {
#pragma unroll
            for (int nf = 0; nf < 2; ++nf) {
#pragma unroll
                for (int r = 0; r < 4; ++r) {
                    float val = acc[mfl][nf][r] + bvl[nf];
                    if constexpr (EPI == EPI_BF16_GELU) val = gelu_f(val);
                    int rm = mfl * 16 + lg * 4 + r;   // local row 0..31
                    int cn = nf * 16 + lr;            // local col 0..31
                    if (vpart) reg[cn * 36 + rm] = (bf16)val;   // [ch][node]
                    else       reg[rm * 36 + cn] = (bf16)val;   // [row][col]
                }
            }
        }
        if (!vpart) {
            bf16* outp = (bf16*)C;
            size_t ld = (EPI == EPI_KV) ? 512 : (size_t)N;
#pragma unroll
            for (int it = 0; it < 4; ++it) {
                int rm = it * 8 + (lane >> 3);
                int cn = (lane & 7) * 4;
                bf16x4 v = *(const bf16x4*)&reg[rm * 36 + cn];
                *(bf16x4*)&outp[(size_t)(m0 + wm * 32 + rm) * ld + (n0 + wn * 32 + cn)] = v;
            }
        } else if constexpr (EPI == EPI_KV) {
            int nb = m0 + wm * 32;
            int g0 = bidx[nb], p0 = pos[nb];
            bool fast = (bidx[nb + 31] == g0) && (pos[nb + 31] == p0 + 31) &&
                        ((p0 & 3) == 0) && (p0 >= 0) && (p0 + 31 < NPG);
            int ch0 = (n0 - 512) + wn * 32;
            if (fast) {
#pragma unroll
                for (int it = 0; it < 4; ++it) {
                    int ch = it * 8 + (lane >> 3);
                    int np = (lane & 7) * 4;
                    bf16x4 v = *(const bf16x4*)&reg[ch * 36 + np];
                    *(bf16x4*)&vt[((size_t)g0 * 512 + ch0 + ch) * 512 + p0 + np] = v;
                }
            } else {
                for (int it = 0; it < 4; ++it) {
                    int ch = it * 8 + (lane >> 3);
#pragma unroll
                    for (int e = 0; e < 4; ++e) {
                        int node = nb + (lane & 7) * 4 + e;
                        int g = bidx[node], p = pos[node];
                        if (p >= 0 && p < NPG)
                            vt[((size_t)g * 512 + ch0 + ch) * 512 + p] = reg[ch * 36 + (lane & 7) * 4 + e];
                    }
                }
            }
        }
    }
}

// ---------------- fused attention: one block per (graph, head) ----------------
// R14: S f16 -> 2 blocks/CU. R15: S/P aliased 33KB -> 4 blocks/CU.
// R16: PV vb hoisted out of mf loop + batched 8-deep.

__global__ __launch_bounds__(256)
void k_attn(const bf16* __restrict__ q, const bf16* __restrict__ kbuf,
            const bf16* __restrict__ vt, const int* __restrict__ inv,
            const int* __restrict__ counts, bf16* __restrict__ ctx)
{
    __shared__ unsigned short SP[32][520];   // f16 scores, then bf16 probs
    const int bh = blockIdx.x;
    const int b = bh >> 3, h = bh & 7;
    const int tid = threadIdx.x;
    const int w = tid >> 6, l = tid & 63;
    const int lr = l & 15, lg = l >> 4;
    const int cnt = counts[b];

    bf16x8 qa[2][2];
#pragma unroll
    for (int mf = 0; mf < 2; ++mf)
#pragma unroll
        for (int ks = 0; ks < 2; ++ks)
            qa[mf][ks] = *(const bf16x8*)&q[(size_t)(b * NQ + mf * 16 + lr) * DIM + h * HDIM + ks * 32 + lg * 8];

    const int nc0 = w * 128;
#pragma unroll
    for (int nf = 0; nf < 8; ++nf) {
        int node = nc0 + nf * 16 + lr;
        int idx = inv[b * NPG + node];
        const bf16* krow = kbuf + (size_t)(idx < 0 ? 0 : idx) * 512 + h * HDIM;
        bf16x8 kb0 = *(const bf16x8*)&krow[lg * 8];
        bf16x8 kb1 = *(const bf16x8*)&krow[32 + lg * 8];
#pragma unroll
        for (int mf = 0; mf < 2; ++mf) {
            f32x4 a = {0.f, 0.f, 0.f, 0.f};
            a = __builtin_amdgcn_mfma_f32_16x16x32_bf16(qa[mf][0], kb0, a, 0, 0, 0);
            a = __builtin_amdgcn_mfma_f32_16x16x32_bf16(qa[mf][1], kb1, a, 0, 0, 0);
#pragma unroll
            for (int r = 0; r < 4; ++r)
                *(_Float16*)&SP[mf * 16 + lg * 4 + r][node] = (_Float16)(a[r] * 0.125f);
        }
    }
    __syncthreads();

#pragma unroll 1
    for (int qi = w * 8; qi < w * 8 + 8; ++qi) {
        float sv[8];
        float mx = -3.4e38f;
#pragma unroll
        for (int e = 0; e < 8; ++e) {
            int c = l + 64 * e;
            sv[e] = (c < cnt) ? (float)*(const _Float16*)&SP[qi][c] : -3.4e38f;
            mx = fmaxf(mx, sv[e]);
        }
#pragma unroll
        for (int o = 32; o; o >>= 1) mx = fmaxf(mx, __shfl_xor(mx, o));
        float sum = 0.f, ev[8];
#pragma unroll
        for (int e = 0; e < 8; ++e) {
            int c = l + 64 * e;
            float s = (c < cnt) ? __expf(sv[e] - mx) : 0.0f;
            ev[e] = s; sum += s;
        }
#pragma unroll
        for (int o = 32; o; o >>= 1) sum += __shfl_xor(sum, o);
        float inv_s = sum > 0.f ? 1.0f / sum : 0.0f;
#pragma unroll
        for (int e = 0; e < 8; ++e)
            *(bf16*)&SP[qi][l + 64 * e] = (bf16)(ev[e] * inv_s);
    }
    __syncthreads();

    // phase 3: ctx = P @ V; vb hoisted (mf-independent), batched 8-deep
    const bf16* vrow = vt + ((size_t)b * 512 + h * HDIM + w * 16 + lr) * 512;
    f32x4 a2[2] = {};
#pragma unroll
    for (int kc8 = 0; kc8 < 2; ++kc8) {
        bf16x8 vb[8];
#pragma unroll
        for (int j = 0; j < 8; ++j)
            vb[j] = *(const bf16x8*)&vrow[(kc8 * 8 + j) * 32 + lg * 8];
#pragma unroll
        for (int mf = 0; mf < 2; ++mf)
#pragma unroll
            for (int j = 0; j < 8; ++j) {
                bf16x8 pa = *(const bf16x8*)&SP[mf * 16 + lr][(kc8 * 8 + j) * 32 + lg * 8];
                a2[mf] = __builtin_amdgcn_mfma_f32_16x16x32_bf16(pa, vb[j], a2[mf], 0, 0, 0);
            }
    }
#pragma unroll
    for (int mf = 0; mf < 2; ++mf)
#pragma unroll
        for (int r = 0; r < 4; ++r)
            ctx[(size_t)(b * NQ + mf * 16 + lg * 4 + r) * DIM + h * HDIM + w * 16 + lr] = (bf16)a2[mf][r];
}

// ---------------- layernorm (one wave per row, f32x4 vectorized) ----------------

template<int MODE>
__global__ __launch_bounds__(256)
void k_ln(const float* __restrict__ x, const float* __restrict__ resid,
          const float* __restrict__ g, const float* __restrict__ bt,
          float* __restrict__ of, bf16* __restrict__ ob, int D)
{
    int wid = blockIdx.x * 4 + (threadIdx.x >> 6);
    int l = threadIdx.x & 63;
    const int nv = D >> 8;     // 2 (D=512) or 3 (D=768)
    const float* xr = x + (size_t)wid * D;
    f32x4 v[3];
    float s = 0.f;
    for (int e = 0; e < nv; ++e) {
        int c = e * 256 + l * 4;
        f32x4 t = *(const f32x4*)&xr[c];
        if (MODE == 0) {
            f32x4 rr = *(const f32x4*)&resid[(size_t)wid * D + c];
            t.x += rr.x; t.y += rr.y; t.z += rr.z; t.w += rr.w;
        }
        v[e] = t; s += t.x + t.y + t.z + t.w;
    }
#pragma unroll
    for (int o = 32; o; o >>= 1) s += __shfl_xor(s, o);
    float mu = s / D;
    float s2 = 0.f;
    for (int e = 0; e < nv; ++e) {
#pragma unroll
        for (int j = 0; j < 4; ++j) { float d = v[e][j] - mu; s2 += d * d; }
    }
#pragma unroll
    for (int o = 32; o; o >>= 1) s2 += __shfl_xor(s2, o);
    float rst = rsqrtf(s2 / D + 1e-5f);
    for (int e = 0; e < nv; ++e) {
        int c = e * 256 + l * 4;
        f32x4 gv = *(const f32x4*)&g[c];
        f32x4 bv = *(const f32x4*)&bt[c];
        f32x4 y;
#pragma unroll
        for (int j = 0; j < 4; ++j) {
            float yy = (v[e][j] - mu) * rst * gv[j] + bv[j];
            if (MODE == 1) yy = gelu_f(yy);
            y[j] = yy;
        }
        if (MODE == 0) *(f32x4*)&of[(size_t)wid * D + c] = y;
        bf16x4 yb = { (bf16)y.x, (bf16)y.y, (bf16)y.z, (bf16)y.w };
        *(bf16x4*)&ob[(size_t)wid * D + c] = yb;
    }
}

// ---------------- host launch ----------------

extern "C" void kernel_launch(void* const* d_in, const int* in_sizes, int n_in,
                              void* d_out, int out_size, void* d_ws, size_t ws_size,
                              hipStream_t stream)
{
    const float* node = (const float*)d_in[0];
    const float* qt   = (const float*)d_in[1];
    const float* ipw  = (const float*)d_in[2];
    const float* ipb  = (const float*)d_in[3];
    const float* opw  = (const float*)d_in[4];
    const float* opb  = (const float*)d_in[5];
    const float* f1w  = (const float*)d_in[6];
    const float* f1b  = (const float*)d_in[7];
    const float* f2w  = (const float*)d_in[8];
    const float* f2b  = (const float*)d_in[9];
    const float* ln1g = (const float*)d_in[10];
    const float* ln1b = (const float*)d_in[11];
    const float* ln2g = (const float*)d_in[12];
    const float* ln2b = (const float*)d_in[13];
    const float* ow1  = (const float*)d_in[14];
    const float* ob1  = (const float*)d_in[15];
    const float* olng = (const float*)d_in[16];
    const float* olnb = (const float*)d_in[17];
    const float* ow2  = (const float*)d_in[18];
    const float* ob2  = (const float*)d_in[19];
    const int*   bidx = (const int*)d_in[20];

    char* ws = (char*)d_ws;
    size_t off = 0;
    auto alloc = [&](size_t bytes) {
        void* p = ws + off;
        off += (bytes + 255) & ~(size_t)255;
        return p;
    };

    int*  counts = (int*)alloc(BATCH * 4);
    int*  starts = (int*)alloc(BATCH * 4);
    int*  pos    = (int*)alloc((size_t)NB * 4);
    int*  inv    = (int*)alloc((size_t)BATCH * NPG * 4);
    bf16* nodeb  = (bf16*)alloc((size_t)NB * DIM * 2);
    bf16* kbuf   = (bf16*)alloc((size_t)NB * DIM * 2);
    bf16* vtb    = (bf16*)alloc((size_t)BATCH * DIM * NPG * 2);
    bf16* wip    = (bf16*)alloc((size_t)NL * 1536 * DIM * 2);
    bf16* wop    = (bf16*)alloc((size_t)NL * DIM * DIM * 2);
    bf16* wf1    = (bf16*)alloc((size_t)NL * 2048 * DIM * 2);
    bf16* wf2    = (bf16*)alloc((size_t)NL * DIM * 2048 * 2);
    bf16* wo1    = (bf16*)alloc((size_t)LMD * DIM * 2);
    bf16* wo2    = (bf16*)alloc((size_t)LMD * LMD * 2);
    float* hf    = (float*)alloc((size_t)ROWS * DIM * 4);
    bf16* hb     = (bf16*)alloc((size_t)ROWS * DIM * 2);
    bf16* qb     = (bf16*)alloc((size_t)ROWS * DIM * 2);
    bf16* ctxb   = (bf16*)alloc((size_t)ROWS * DIM * 2);
    float* tmp   = (float*)alloc((size_t)ROWS * LMD * 4);
    bf16* fmid   = (bf16*)alloc((size_t)ROWS * 2048 * 2);
    bf16* omid   = (bf16*)alloc((size_t)ROWS * LMD * 2);
    (void)ws_size; (void)in_sizes; (void)n_in; (void)out_size;

    k_init_meta<<<512, 256, 0, stream>>>(counts, inv);
    k_count<<<NB / 256, 256, 0, stream>>>(bidx, counts);
    k_scan<<<1, BATCH, 0, stream>>>(counts, starts);
    k_posinv<<<NB / 256, 256, 0, stream>>>(bidx, starts, pos, inv);
    k_f32_to_bf16<<<2048, 256, 0, stream>>>(node, nodeb, (long)NB * DIM / 4);
    k_f32_to_bf16<<<256, 256, 0, stream>>>(ipw, wip, (long)NL * 1536 * DIM / 4);
    k_f32_to_bf16<<<256, 256, 0, stream>>>(opw, wop, (long)NL * DIM * DIM / 4);
    k_f32_to_bf16<<<256, 256, 0, stream>>>(f1w, wf1, (long)NL * 2048 * DIM / 4);
    k_f32_to_bf16<<<256, 256, 0, stream>>>(f2w, wf2, (long)NL * DIM * 2048 / 4);
    k_f32_to_bf16<<<256, 256, 0, stream>>>(ow1, wo1, (long)LMD * DIM / 4);
    k_f32_to_bf16<<<256, 256, 0, stream>>>(ow2, wo2, (long)LMD * LMD / 4);
    k_init_h<<<2048, 256, 0, stream>>>(qt, hf, hb);

    for (int lyr = 0; lyr < NL; ++lyr) {
        const bf16* wq  = wip + (size_t)lyr * 1536 * DIM;
        const bf16* wkv = wq + (size_t)512 * DIM;
        const float* bq  = ipb + lyr * 1536;
        const float* bkv = bq + 512;

        dim3 gkv(1024 / 128, NB / 128);
        k_ring<EPI_KV><<<gkv, 1024, 0, stream>>>(nodeb, wkv, bkv, kbuf, DIM, 1024, vtb, bidx, pos);

        dim3 gq(DIM / 128, ROWS / 128);
        k_ring<EPI_BF16><<<gq, 1024, 0, stream>>>(hb, wq, bq, qb, DIM, DIM,
                                                  nullptr, nullptr, nullptr);

        k_attn<<<BATCH * NH, 256, 0, stream>>>(qb, kbuf, vtb, inv, counts, ctxb);

        k_ring<EPI_F32><<<gq, 1024, 0, stream>>>(ctxb, wop + (size_t)lyr * DIM * DIM,
                                                 opb + lyr * DIM, tmp, DIM, DIM,
                                                 nullptr, nullptr, nullptr);
        k_ln<0><<<ROWS / 4, 256, 0, stream>>>(tmp, hf, ln1g + lyr * DIM, ln1b + lyr * DIM, hf, hb, DIM);

        dim3 gf1(2048 / 128, ROWS / 128);
        k_ring<EPI_BF16_GELU><<<gf1, 1024, 0, stream>>>(hb, wf1 + (size_t)lyr * 2048 * DIM,
                                                        f1b + lyr * 2048, fmid, DIM, 2048,
                                                        nullptr, nullptr, nullptr);
        k_ring<EPI_F32><<<gq, 1024, 0, stream>>>(fmid, wf2 + (size_t)lyr * DIM * 2048,
                                                 f2b + lyr * DIM, tmp, 2048, DIM,
                                                 nullptr, nullptr, nullptr);
        k_ln<0><<<ROWS / 4, 256, 0, stream>>>(tmp, hf, ln2g + lyr * DIM, ln2b + lyr * DIM, hf, hb, DIM);
    }

    dim3 go1(LMD / 128, ROWS / 128);
    k_ring<EPI_F32><<<go1, 1024, 0, stream>>>(hb, wo1, ob1, tmp, DIM, LMD,
                                              nullptr, nullptr, nullptr);
    k_ln<1><<<ROWS / 4, 256, 0, stream>>>(tmp, nullptr, olng, olnb, nullptr, omid, LMD);
    k_ring<EPI_F32><<<go1, 1024, 0, stream>>>(omid, wo2, ob2, (float*)d_out, LMD, LMD,
                                              nullptr, nullptr, nullptr);
}

// Round 21
// 1123.929 us; speedup vs baseline: 1.1554x; 1.0165x over previous
//
#include <hip/hip_runtime.h>
#include <hip/hip_bf16.h>
#include <math.h>

typedef __bf16 bf16;
typedef bf16 bf16x8 __attribute__((ext_vector_type(8)));
typedef bf16 bf16x4 __attribute__((ext_vector_type(4)));
typedef float f32x4 __attribute__((ext_vector_type(4)));

#define NB    131072
#define DIM   512
#define BATCH 256
#define NPG   512
#define NQ    32
#define NH    8
#define HDIM  64
#define LMD   768
#define NL    2
#define ROWS  (BATCH*NQ)   // 8192

template<int N> struct ic { static constexpr int v = N; };

__device__ __forceinline__ float gelu_f(float x) {
    return 0.5f * x * (1.0f + erff(x * 0.70710678118654752f));
}

// ---------------- small setup kernels ----------------

__global__ void k_init_meta(int* counts, int* inv) {
    int i = blockIdx.x * blockDim.x + threadIdx.x;
    if (i < BATCH) counts[i] = 0;
    for (int j = i; j < BATCH * NPG; j += gridDim.x * blockDim.x) inv[j] = -1;
}

__global__ void k_count(const int* __restrict__ bidx, int* counts) {
    int i = blockIdx.x * blockDim.x + threadIdx.x;
    if (i < NB) atomicAdd(&counts[bidx[i]], 1);
}

__global__ void k_scan(const int* __restrict__ counts, int* __restrict__ starts) {
    __shared__ int sh[BATCH];
    int t = threadIdx.x;
    sh[t] = counts[t];
    __syncthreads();
    for (int o = 1; o < BATCH; o <<= 1) {
        int v = (t >= o) ? sh[t - o] : 0;
        __syncthreads();
        sh[t] += v;
        __syncthreads();
    }
    starts[t] = sh[t] - counts[t];
}

__global__ void k_posinv(const int* __restrict__ bidx, const int* __restrict__ starts,
                         int* __restrict__ pos, int* __restrict__ inv) {
    int i = blockIdx.x * blockDim.x + threadIdx.x;
    if (i < NB) {
        int b = bidx[i];
        int p = i - starts[b];
        pos[i] = p;
        if (p >= 0 && p < NPG) inv[b * NPG + p] = i;
    }
}

__global__ void k_f32_to_bf16(const float* __restrict__ src, bf16* __restrict__ dst, long n4) {
    long i = blockIdx.x * (long)blockDim.x + threadIdx.x;
    long stride = (long)gridDim.x * blockDim.x;
    for (; i < n4; i += stride) {
        f32x4 v = ((const f32x4*)src)[i];
        bf16x4 o = { (bf16)v.x, (bf16)v.y, (bf16)v.z, (bf16)v.w };
        ((bf16x4*)dst)[i] = o;
    }
}

// R21: fused setup — all 6 weight f32->bf16 conversions + init_h in ONE
// launch (was 7). Segment bounds are compile-time; arithmetic identical.
#define SEG0 393216            // ipw   (NL*1536*DIM/4)
#define SEG1 (SEG0 + 131072)   // opw   (NL*DIM*DIM/4)
#define SEG2 (SEG1 + 524288)   // f1w   (NL*2048*DIM/4)
#define SEG3 (SEG2 + 524288)   // f2w
#define SEG4 (SEG3 + 98304)    // ow1   (LMD*DIM/4)
#define SEG5 (SEG4 + 147456)   // ow2   (LMD*LMD/4)
#define SEGT (SEG5 + 1048576)  // init_h (ROWS*DIM/4)

__device__ __forceinline__ void cvt4(const float* s, bf16* d, int i) {
    f32x4 v = ((const f32x4*)s)[i];
    bf16x4 o = { (bf16)v.x, (bf16)v.y, (bf16)v.z, (bf16)v.w };
    ((bf16x4*)d)[i] = o;
}

__global__ void k_setup(const float* __restrict__ ipw, bf16* __restrict__ wip,
                        const float* __restrict__ opw, bf16* __restrict__ wop,
                        const float* __restrict__ f1w, bf16* __restrict__ wf1,
                        const float* __restrict__ f2w, bf16* __restrict__ wf2,
                        const float* __restrict__ ow1, bf16* __restrict__ wo1,
                        const float* __restrict__ ow2, bf16* __restrict__ wo2,
                        const float* __restrict__ qt, float* __restrict__ hf,
                        bf16* __restrict__ hb)
{
    for (int i = blockIdx.x * blockDim.x + threadIdx.x; i < SEGT;
         i += gridDim.x * blockDim.x) {
        if (i < SEG0)      cvt4(ipw, wip, i);
        else if (i < SEG1) cvt4(opw, wop, i - SEG0);
        else if (i < SEG2) cvt4(f1w, wf1, i - SEG1);
        else if (i < SEG3) cvt4(f2w, wf2, i - SEG2);
        else if (i < SEG4) cvt4(ow1, wo1, i - SEG3);
        else if (i < SEG5) cvt4(ow2, wo2, i - SEG4);
        else {
            int j = i - SEG5;                    // f32x4 index into h
            f32x4 v = ((const f32x4*)qt)[j & 4095];   // NQ*DIM/4 = 4096
            ((f32x4*)hf)[j] = v;
            bf16x4 o = { (bf16)v.x, (bf16)v.y, (bf16)v.z, (bf16)v.w };
            ((bf16x4*)hb)[j] = o;
        }
    }
}

#define EPI_BF16      0
#define EPI_BF16_GELU 1
#define EPI_F32       2
#define EPI_KV        3

// ===== 128x128 ring GEMM — R18 (final): 16 waves (4Mx4N), 32x32/wave =====
// 4-slot / 3-tile-lookahead / 1-tile-per-barrier schedule (verified R9/R13/
// R17/R18; R11 ERRATUM: every comp preceded by all-waves counted-vmcnt ->
// barrier). 1024 threads = 16 waves, per-wave 32x32 (acc[2][2] = 16 AGPR,
// av[2]+bv[2], one staging pointer/thread) -> <=64 total regs -> 32 waves/CU
// (2 blocks x 16), 84% occupancy (measured). R19 ERRATUM: 32x32x16 MFMA
// blew up LDS bank conflicts 9x — kept 16x16x32.

template<int EPI>
__global__ __launch_bounds__(1024)
void k_ring(const bf16* __restrict__ A, const bf16* __restrict__ B,
            const float* __restrict__ bias, void* __restrict__ C,
            int K, int N,
            bf16* __restrict__ vt, const int* __restrict__ bidx,
            const int* __restrict__ pos)
{
    // per slot: A elems [0,4096) (128x32), B elems [4096,8192) (128x32)
    __shared__ bf16 L[4][8192];
    const int tid = threadIdx.x;
    const int w = tid >> 6, lane = tid & 63;

    int nwg = gridDim.x * gridDim.y;
    int lin = blockIdx.y * gridDim.x + blockIdx.x;
    int cpx = nwg >> 3;
    int swzb = (lin & 7) * cpx + (lin >> 3);
    const int n0 = (swzb % gridDim.x) * 128;
    const int m0 = (swzb / gridDim.x) * 128;

    const int wm = w >> 2, wn = w & 3;            // 4 x 4 wave grid
    const int lr = lane & 15, lg = lane >> 4;
    const int nkt = K >> 5;

    f32x4 acc[2][2] = {};

    // ---- staging addressing: one load per thread per tile ----
    const int t2 = tid & 511;                      // index within A- or B-half
    const int rSt = t2 >> 2;                       // 0..127
    const int cSw = (t2 & 3) ^ ((rSt >> 1) & 3);   // both-sides swizzle rule
    const bf16* ps = (tid < 512)
        ? A + (size_t)(m0 + rSt) * K + cSw * 8
        : B + (size_t)(n0 + rSt) * K + cSw * 8;
    bf16* lds = &L[0][(tid < 512 ? 0 : 4096) + t2 * 8];

    // ---- hoisted fragment read indices (elements into L[0]) ----
    int iA[2], iB[2];
#pragma unroll
    for (int mf = 0; mf < 2; ++mf) {
        int row = wm * 32 + mf * 16 + lr;
        iA[mf] = row * 32 + (lg ^ ((row >> 1) & 3)) * 8;
    }
#pragma unroll
    for (int nf = 0; nf < 2; ++nf) {
        int col = wn * 32 + nf * 16 + lr;
        iB[nf] = 4096 + col * 32 + (lg ^ ((col >> 1) & 3)) * 8;
    }
    const bf16* Lf = &L[0][0];

    auto stage = [&](auto S) {   // stages next sequential K-tile into slot S
        constexpr int c = decltype(S)::v;
        __builtin_amdgcn_global_load_lds((const __attribute__((address_space(1))) void*)ps,
            (__attribute__((address_space(3))) void*)(lds + c * 8192), 16, 0, 0);
        ps += 32;
    };

    auto comp = [&](auto S) {
        constexpr int c = decltype(S)::v;
        bf16x8 av[2], bv[2];
#pragma unroll
        for (int mf = 0; mf < 2; ++mf)
            av[mf] = *(const bf16x8*)&Lf[iA[mf] + c * 8192];
#pragma unroll
        for (int nf = 0; nf < 2; ++nf)
            bv[nf] = *(const bf16x8*)&Lf[iB[nf] + c * 8192];
        __builtin_amdgcn_s_setprio(1);
#pragma unroll
        for (int mf = 0; mf < 2; ++mf)
#pragma unroll
            for (int nf = 0; nf < 2; ++nf)
                acc[mf][nf] = __builtin_amdgcn_mfma_f32_16x16x32_bf16(av[mf], bv[nf], acc[mf][nf], 0, 0, 0);
        __builtin_amdgcn_s_setprio(0);
    };

    auto step = [&](auto C_, auto CN_, int t) {
        if (t + 3 < nkt) {
            stage(CN_);
            comp(C_);
            asm volatile("s_waitcnt vmcnt(2)" ::: "memory");
        } else {
            comp(C_);
            asm volatile("s_waitcnt vmcnt(0)" ::: "memory");
        }
        __builtin_amdgcn_s_barrier();
    };

    stage(ic<0>{});                 // tile 0
    stage(ic<1>{});                 // tile 1
    stage(ic<2>{});                 // tile 2
    asm volatile("s_waitcnt vmcnt(2)" ::: "memory");   // tile 0 landed
    __builtin_amdgcn_s_barrier();

    int t = 0;
#pragma unroll 1
    for (; t + 4 <= nkt; t += 4) {
        step(ic<0>{}, ic<3>{}, t);
        step(ic<1>{}, ic<0>{}, t + 1);
        step(ic<2>{}, ic<1>{}, t + 2);
        step(ic<3>{}, ic<2>{}, t + 3);
    }
    if (t < nkt) { step(ic<0>{}, ic<3>{}, t); ++t; }
    if (t < nkt) { step(ic<1>{}, ic<0>{}, t); ++t; }
    if (t < nkt) { step(ic<2>{}, ic<1>{}, t); ++t; }

    // ---- epilogue ----
    float bvl[2];
#pragma unroll
    for (int nf = 0; nf < 2; ++nf)
        bvl[nf] = bias ? bias[n0 + wn * 32 + nf * 16 + lr] : 0.0f;

    if constexpr (EPI == EPI_F32) {
        float* out = (float*)C;
#pragma unroll
        for (int mfl = 0; mfl < 2; ++mfl) {
#pragma unroll
            for (int nf = 0; nf < 2; ++nf) {
                int c = n0 + wn * 32 + nf * 16 + lr;
#pragma unroll
                for (int r = 0; r < 4; ++r)
                    out[(size_t)(m0 + wm * 32 + mfl * 16 + lg * 4 + r) * N + c] = acc[mfl][nf][r] + bvl[nf];
            }
        }
    } else {
        __syncthreads();   // LDS free for reuse
        // per-wave repack region: [32][36] = 1152 elems; 16 x 1152 <= 32768.
        bf16* reg = &L[0][0] + w * 1152;
        const bool vpart = (EPI == EPI_KV) && (n0 >= 512);
#pragma unroll
        for (int mfl = 0; mfl < 2; ++mfl) {
#pragma unroll
            for (int nf = 0; nf < 2; ++nf) {
#pragma unroll
                for (int r = 0; r < 4; ++r) {
                    float val = acc[mfl][nf][r] + bvl[nf];
                    if constexpr (EPI == EPI_BF16_GELU) val = gelu_f(val);
                    int rm = mfl * 16 + lg * 4 + r;   // local row 0..31
                    int cn = nf * 16 + lr;            // local col 0..31
                    if (vpart) reg[cn * 36 + rm] = (bf16)val;   // [ch][node]
                    else       reg[rm * 36 + cn] = (bf16)val;   // [row][col]
                }
            }
        }
        if (!vpart) {
            bf16* outp = (bf16*)C;
            size_t ld = (EPI == EPI_KV) ? 512 : (size_t)N;
#pragma unroll
            for (int it = 0; it < 4; ++it) {
                int rm = it * 8 + (lane >> 3);
                int cn = (lane & 7) * 4;
                bf16x4 v = *(const bf16x4*)&reg[rm * 36 + cn];
                *(bf16x4*)&outp[(size_t)(m0 + wm * 32 + rm) * ld + (n0 + wn * 32 + cn)] = v;
            }
        } else if constexpr (EPI == EPI_KV) {
            int nb = m0 + wm * 32;
            int g0 = bidx[nb], p0 = pos[nb];
            bool fast = (bidx[nb + 31] == g0) && (pos[nb + 31] == p0 + 31) &&
                        ((p0 & 3) == 0) && (p0 >= 0) && (p0 + 31 < NPG);
            int ch0 = (n0 - 512) + wn * 32;
            if (fast) {
#pragma unroll
                for (int it = 0; it < 4; ++it) {
                    int ch = it * 8 + (lane >> 3);
                    int np = (lane & 7) * 4;
                    bf16x4 v = *(const bf16x4*)&reg[ch * 36 + np];
                    *(bf16x4*)&vt[((size_t)g0 * 512 + ch0 + ch) * 512 + p0 + np] = v;
                }
            } else {
                for (int it = 0; it < 4; ++it) {
                    int ch = it * 8 + (lane >> 3);
#pragma unroll
                    for (int e = 0; e < 4; ++e) {
                        int node = nb + (lane & 7) * 4 + e;
                        int g = bidx[node], p = pos[node];
                        if (p >= 0 && p < NPG)
                            vt[((size_t)g * 512 + ch0 + ch) * 512 + p] = reg[ch * 36 + (lane & 7) * 4 + e];
                    }
                }
            }
        }
    }
}

// ---------------- fused attention: one block per (graph, head) ----------------
// R14: S f16 -> 2 blocks/CU. R15: S/P aliased 33KB -> 4 blocks/CU.
// R16: PV vb hoisted out of mf loop + batched 8-deep.

__global__ __launch_bounds__(256)
void k_attn(const bf16* __restrict__ q, const bf16* __restrict__ kbuf,
            const bf16* __restrict__ vt, const int* __restrict__ inv,
            const int* __restrict__ counts, bf16* __restrict__ ctx)
{
    __shared__ unsigned short SP[32][520];   // f16 scores, then bf16 probs
    const int bh = blockIdx.x;
    const int b = bh >> 3, h = bh & 7;
    const int tid = threadIdx.x;
    const int w = tid >> 6, l = tid & 63;
    const int lr = l & 15, lg = l >> 4;
    const int cnt = counts[b];

    bf16x8 qa[2][2];
#pragma unroll
    for (int mf = 0; mf < 2; ++mf)
#pragma unroll
        for (int ks = 0; ks < 2; ++ks)
            qa[mf][ks] = *(const bf16x8*)&q[(size_t)(b * NQ + mf * 16 + lr) * DIM + h * HDIM + ks * 32 + lg * 8];

    const int nc0 = w * 128;
#pragma unroll
    for (int nf = 0; nf < 8; ++nf) {
        int node = nc0 + nf * 16 + lr;
        int idx = inv[b * NPG + node];
        const bf16* krow = kbuf + (size_t)(idx < 0 ? 0 : idx) * 512 + h * HDIM;
        bf16x8 kb0 = *(const bf16x8*)&krow[lg * 8];
        bf16x8 kb1 = *(const bf16x8*)&krow[32 + lg * 8];
#pragma unroll
        for (int mf = 0; mf < 2; ++mf) {
            f32x4 a = {0.f, 0.f, 0.f, 0.f};
            a = __builtin_amdgcn_mfma_f32_16x16x32_bf16(qa[mf][0], kb0, a, 0, 0, 0);
            a = __builtin_amdgcn_mfma_f32_16x16x32_bf16(qa[mf][1], kb1, a, 0, 0, 0);
#pragma unroll
            for (int r = 0; r < 4; ++r)
                *(_Float16*)&SP[mf * 16 + lg * 4 + r][node] = (_Float16)(a[r] * 0.125f);
        }
    }
    __syncthreads();

#pragma unroll 1
    for (int qi = w * 8; qi < w * 8 + 8; ++qi) {
        float sv[8];
        float mx = -3.4e38f;
#pragma unroll
        for (int e = 0; e < 8; ++e) {
            int c = l + 64 * e;
            sv[e] = (c < cnt) ? (float)*(const _Float16*)&SP[qi][c] : -3.4e38f;
            mx = fmaxf(mx, sv[e]);
        }
#pragma unroll
        for (int o = 32; o; o >>= 1) mx = fmaxf(mx, __shfl_xor(mx, o));
        float sum = 0.f, ev[8];
#pragma unroll
        for (int e = 0; e < 8; ++e) {
            int c = l + 64 * e;
            float s = (c < cnt) ? __expf(sv[e] - mx) : 0.0f;
            ev[e] = s; sum += s;
        }
#pragma unroll
        for (int o = 32; o; o >>= 1) sum += __shfl_xor(sum, o);
        float inv_s = sum > 0.f ? 1.0f / sum : 0.0f;
#pragma unroll
        for (int e = 0; e < 8; ++e)
            *(bf16*)&SP[qi][l + 64 * e] = (bf16)(ev[e] * inv_s);
    }
    __syncthreads();

    // phase 3: ctx = P @ V; vb hoisted (mf-independent), batched 8-deep
    const bf16* vrow = vt + ((size_t)b * 512 + h * HDIM + w * 16 + lr) * 512;
    f32x4 a2[2] = {};
#pragma unroll
    for (int kc8 = 0; kc8 < 2; ++kc8) {
        bf16x8 vb[8];
#pragma unroll
        for (int j = 0; j < 8; ++j)
            vb[j] = *(const bf16x8*)&vrow[(kc8 * 8 + j) * 32 + lg * 8];
#pragma unroll
        for (int mf = 0; mf < 2; ++mf)
#pragma unroll
            for (int j = 0; j < 8; ++j) {
                bf16x8 pa = *(const bf16x8*)&SP[mf * 16 + lr][(kc8 * 8 + j) * 32 + lg * 8];
                a2[mf] = __builtin_amdgcn_mfma_f32_16x16x32_bf16(pa, vb[j], a2[mf], 0, 0, 0);
            }
    }
#pragma unroll
    for (int mf = 0; mf < 2; ++mf)
#pragma unroll
        for (int r = 0; r < 4; ++r)
            ctx[(size_t)(b * NQ + mf * 16 + lg * 4 + r) * DIM + h * HDIM + w * 16 + lr] = (bf16)a2[mf][r];
}

// ---------------- layernorm (one wave per row, f32x4 vectorized) ----------------

template<int MODE>
__global__ __launch_bounds__(256)
void k_ln(const float* __restrict__ x, const float* __restrict__ resid,
          const float* __restrict__ g, const float* __restrict__ bt,
          float* __restrict__ of, bf16* __restrict__ ob, int D)
{
    int wid = blockIdx.x * 4 + (threadIdx.x >> 6);
    int l = threadIdx.x & 63;
    const int nv = D >> 8;     // 2 (D=512) or 3 (D=768)
    const float* xr = x + (size_t)wid * D;
    f32x4 v[3];
    float s = 0.f;
    for (int e = 0; e < nv; ++e) {
        int c = e * 256 + l * 4;
        f32x4 t = *(const f32x4*)&xr[c];
        if (MODE == 0) {
            f32x4 rr = *(const f32x4*)&resid[(size_t)wid * D + c];
            t.x += rr.x; t.y += rr.y; t.z += rr.z; t.w += rr.w;
        }
        v[e] = t; s += t.x + t.y + t.z + t.w;
    }
#pragma unroll
    for (int o = 32; o; o >>= 1) s += __shfl_xor(s, o);
    float mu = s / D;
    float s2 = 0.f;
    for (int e = 0; e < nv; ++e) {
#pragma unroll
        for (int j = 0; j < 4; ++j) { float d = v[e][j] - mu; s2 += d * d; }
    }
#pragma unroll
    for (int o = 32; o; o >>= 1) s2 += __shfl_xor(s2, o);
    float rst = rsqrtf(s2 / D + 1e-5f);
    for (int e = 0; e < nv; ++e) {
        int c = e * 256 + l * 4;
        f32x4 gv = *(const f32x4*)&g[c];
        f32x4 bv = *(const f32x4*)&bt[c];
        f32x4 y;
#pragma unroll
        for (int j = 0; j < 4; ++j) {
            float yy = (v[e][j] - mu) * rst * gv[j] + bv[j];
            if (MODE == 1) yy = gelu_f(yy);
            y[j] = yy;
        }
        if (MODE == 0) *(f32x4*)&of[(size_t)wid * D + c] = y;
        bf16x4 yb = { (bf16)y.x, (bf16)y.y, (bf16)y.z, (bf16)y.w };
        *(bf16x4*)&ob[(size_t)wid * D + c] = yb;
    }
}

// ---------------- host launch ----------------

extern "C" void kernel_launch(void* const* d_in, const int* in_sizes, int n_in,
                              void* d_out, int out_size, void* d_ws, size_t ws_size,
                              hipStream_t stream)
{
    const float* node = (const float*)d_in[0];
    const float* qt   = (const float*)d_in[1];
    const float* ipw  = (const float*)d_in[2];
    const float* ipb  = (const float*)d_in[3];
    const float* opw  = (const float*)d_in[4];
    const float* opb  = (const float*)d_in[5];
    const float* f1w  = (const float*)d_in[6];
    const float* f1b  = (const float*)d_in[7];
    const float* f2w  = (const float*)d_in[8];
    const float* f2b  = (const float*)d_in[9];
    const float* ln1g = (const float*)d_in[10];
    const float* ln1b = (const float*)d_in[11];
    const float* ln2g = (const float*)d_in[12];
    const float* ln2b = (const float*)d_in[13];
    const float* ow1  = (const float*)d_in[14];
    const float* ob1  = (const float*)d_in[15];
    const float* olng = (const float*)d_in[16];
    const float* olnb = (const float*)d_in[17];
    const float* ow2  = (const float*)d_in[18];
    const float* ob2  = (const float*)d_in[19];
    const int*   bidx = (const int*)d_in[20];

    char* ws = (char*)d_ws;
    size_t off = 0;
    auto alloc = [&](size_t bytes) {
        void* p = ws + off;
        off += (bytes + 255) & ~(size_t)255;
        return p;
    };

    int*  counts = (int*)alloc(BATCH * 4);
    int*  starts = (int*)alloc(BATCH * 4);
    int*  pos    = (int*)alloc((size_t)NB * 4);
    int*  inv    = (int*)alloc((size_t)BATCH * NPG * 4);
    bf16* nodeb  = (bf16*)alloc((size_t)NB * DIM * 2);
    bf16* kbuf   = (bf16*)alloc((size_t)NB * DIM * 2);
    bf16* vtb    = (bf16*)alloc((size_t)BATCH * DIM * NPG * 2);
    bf16* wip    = (bf16*)alloc((size_t)NL * 1536 * DIM * 2);
    bf16* wop    = (bf16*)alloc((size_t)NL * DIM * DIM * 2);
    bf16* wf1    = (bf16*)alloc((size_t)NL * 2048 * DIM * 2);
    bf16* wf2    = (bf16*)alloc((size_t)NL * DIM * 2048 * 2);
    bf16* wo1    = (bf16*)alloc((size_t)LMD * DIM * 2);
    bf16* wo2    = (bf16*)alloc((size_t)LMD * LMD * 2);
    float* hf    = (float*)alloc((size_t)ROWS * DIM * 4);
    bf16* hb     = (bf16*)alloc((size_t)ROWS * DIM * 2);
    bf16* qb     = (bf16*)alloc((size_t)ROWS * DIM * 2);
    bf16* ctxb   = (bf16*)alloc((size_t)ROWS * DIM * 2);
    float* tmp   = (float*)alloc((size_t)ROWS * LMD * 4);
    bf16* fmid   = (bf16*)alloc((size_t)ROWS * 2048 * 2);
    bf16* omid   = (bf16*)alloc((size_t)ROWS * LMD * 2);
    (void)ws_size; (void)in_sizes; (void)n_in; (void)out_size;

    k_init_meta<<<512, 256, 0, stream>>>(counts, inv);
    k_count<<<NB / 256, 256, 0, stream>>>(bidx, counts);
    k_scan<<<1, BATCH, 0, stream>>>(counts, starts);
    k_posinv<<<NB / 256, 256, 0, stream>>>(bidx, starts, pos, inv);
    k_f32_to_bf16<<<2048, 256, 0, stream>>>(node, nodeb, (long)NB * DIM / 4);
    k_setup<<<2048, 256, 0, stream>>>(ipw, wip, opw, wop, f1w, wf1, f2w, wf2,
                                      ow1, wo1, ow2, wo2, qt, hf, hb);

    for (int lyr = 0; lyr < NL; ++lyr) {
        const bf16* wq  = wip + (size_t)lyr * 1536 * DIM;
        const bf16* wkv = wq + (size_t)512 * DIM;
        const float* bq  = ipb + lyr * 1536;
        const float* bkv = bq + 512;

        dim3 gkv(1024 / 128, NB / 128);
        k_ring<EPI_KV><<<gkv, 1024, 0, stream>>>(nodeb, wkv, bkv, kbuf, DIM, 1024, vtb, bidx, pos);

        dim3 gq(DIM / 128, ROWS / 128);
        k_ring<EPI_BF16><<<gq, 1024, 0, stream>>>(hb, wq, bq, qb, DIM, DIM,
                                                  nullptr, nullptr, nullptr);

        k_attn<<<BATCH * NH, 256, 0, stream>>>(qb, kbuf, vtb, inv, counts, ctxb);

        k_ring<EPI_F32><<<gq, 1024, 0, stream>>>(ctxb, wop + (size_t)lyr * DIM * DIM,
                                                 opb + lyr * DIM, tmp, DIM, DIM,
                                                 nullptr, nullptr, nullptr);
        k_ln<0><<<ROWS / 4, 256, 0, stream>>>(tmp, hf, ln1g + lyr * DIM, ln1b + lyr * DIM, hf, hb, DIM);

        dim3 gf1(2048 / 128, ROWS / 128);
        k_ring<EPI_BF16_GELU><<<gf1, 1024, 0, stream>>>(hb, wf1 + (size_t)lyr * 2048 * DIM,
                                                        f1b + lyr * 2048, fmid, DIM, 2048,
                                                        nullptr, nullptr, nullptr);
        k_ring<EPI_F32><<<gq, 1024, 0, stream>>>(fmid, wf2 + (size_t)lyr * DIM * 2048,
                                                 f2b + lyr * DIM, tmp, 2048, DIM,
                                                 nullptr, nullptr, nullptr);
        k_ln<0><<<ROWS / 4, 256, 0, stream>>>(tmp, hf, ln2g + lyr * DIM, ln2b + lyr * DIM, hf, hb, DIM);
    }

    dim3 go1(LMD / 128, ROWS / 128);
    k_ring<EPI_F32><<<go1, 1024, 0, stream>>>(hb, wo1, ob1, tmp, DIM, LMD,
                                              nullptr, nullptr, nullptr);
    k_ln<1><<<ROWS / 4, 256, 0, stream>>>(tmp, nullptr, olng, olnb, nullptr, omid, LMD);
    k_ring<EPI_F32><<<go1, 1024, 0, stream>>>(omid, wo2, ob2, (float*)d_out, LMD, LMD,
                                              nullptr, nullptr, nullptr);
}